// Round 1
// baseline (80151.270 us; speedup 1.0000x reference)
//
#include <hip/hip_runtime.h>
#include <cstddef>

#define Bc 16
#define Tt 32
#define Hh 40
#define Ww 40
#define Fc 40
#define C4 160
#define BN_EPS_ 1e-3f

__device__ __forceinline__ float hsig(float x) {
    return fminf(fmaxf(0.2f * x + 0.5f, 0.0f), 1.0f);
}

// ---------------------------------------------------------------------------
// Kernel 1: z[b,y,x,ch] = bias[ch] + conv3x3(x_t, Wx)[ch] + conv3x3(h, Wh)[ch]
// Block: (160 ch, 2 rows). Each thread accumulates 8 x-positions (registers).
// Weight slice per (dy,dx) staged in LDS; input reads are float4 over ci and
// wave-uniform across ch lanes (broadcast).
// ---------------------------------------------------------------------------
template <int CIN>
__global__ __launch_bounds__(320) void conv_gates(
    const float* __restrict__ xin,   // [B,T,H,W,CIN]
    const float* __restrict__ h,     // [B,H,W,F]
    const float* __restrict__ Wx,    // [3,3,CIN,160]
    const float* __restrict__ Wh,    // [3,3,F,160]
    const float* __restrict__ bias,  // [160]
    float* __restrict__ z,           // [B,H,W,160]
    int t)
{
    __shared__ float wss[(CIN + Fc) * C4];

    const int ch = threadIdx.x;            // 0..159
    const int ty = threadIdx.y;            // 0..1
    const int x0 = blockIdx.x * 8;         // 0,8,16,24,32
    const int y  = blockIdx.y * 2 + ty;    // 0..39
    const int b  = blockIdx.z;
    const int tidl = ty * 160 + ch;        // 0..319

    float acc[8];
    const float bv = bias[ch];
#pragma unroll
    for (int p = 0; p < 8; ++p) acc[p] = bv;

    const float* xin_bt = xin + (size_t)(b * Tt + t) * Hh * Ww * CIN;
    const float* h_b    = h + (size_t)b * Hh * Ww * Fc;

    for (int dy = 0; dy < 3; ++dy) {
        for (int dx = 0; dx < 3; ++dx) {
            __syncthreads();
            const float* wxs = Wx + (size_t)((dy * 3 + dx) * CIN) * C4;
            const float* whs = Wh + (size_t)((dy * 3 + dx) * Fc) * C4;
            for (int i = tidl; i < CIN * C4; i += 320) wss[i] = wxs[i];
            for (int i = tidl; i < Fc * C4; i += 320) wss[CIN * C4 + i] = whs[i];
            __syncthreads();

            const int yy = y + dy - 1;
            if (yy < 0 || yy >= Hh) continue;  // all threads still reach next barrier

            // ---- x-input part ----
            if constexpr (CIN % 4 == 0) {
                for (int c4 = 0; c4 < CIN / 4; ++c4) {
                    const float w0 = wss[(c4 * 4 + 0) * C4 + ch];
                    const float w1 = wss[(c4 * 4 + 1) * C4 + ch];
                    const float w2 = wss[(c4 * 4 + 2) * C4 + ch];
                    const float w3 = wss[(c4 * 4 + 3) * C4 + ch];
#pragma unroll
                    for (int p = 0; p < 8; ++p) {
                        const int xx = x0 + p + dx - 1;
                        if (xx >= 0 && xx < Ww) {
                            const float4 v = *reinterpret_cast<const float4*>(
                                xin_bt + ((size_t)yy * Ww + xx) * CIN + c4 * 4);
                            acc[p] = fmaf(v.x, w0, acc[p]);
                            acc[p] = fmaf(v.y, w1, acc[p]);
                            acc[p] = fmaf(v.z, w2, acc[p]);
                            acc[p] = fmaf(v.w, w3, acc[p]);
                        }
                    }
                }
            } else {
                for (int ci = 0; ci < CIN; ++ci) {
                    const float w = wss[ci * C4 + ch];
#pragma unroll
                    for (int p = 0; p < 8; ++p) {
                        const int xx = x0 + p + dx - 1;
                        if (xx >= 0 && xx < Ww) {
                            const float v = xin_bt[((size_t)yy * Ww + xx) * CIN + ci];
                            acc[p] = fmaf(v, w, acc[p]);
                        }
                    }
                }
            }

            // ---- h part (always F=40 channels) ----
            for (int c4 = 0; c4 < Fc / 4; ++c4) {
                const float w0 = wss[CIN * C4 + (c4 * 4 + 0) * C4 + ch];
                const float w1 = wss[CIN * C4 + (c4 * 4 + 1) * C4 + ch];
                const float w2 = wss[CIN * C4 + (c4 * 4 + 2) * C4 + ch];
                const float w3 = wss[CIN * C4 + (c4 * 4 + 3) * C4 + ch];
#pragma unroll
                for (int p = 0; p < 8; ++p) {
                    const int xx = x0 + p + dx - 1;
                    if (xx >= 0 && xx < Ww) {
                        const float4 v = *reinterpret_cast<const float4*>(
                            h_b + ((size_t)yy * Ww + xx) * Fc + c4 * 4);
                        acc[p] = fmaf(v.x, w0, acc[p]);
                        acc[p] = fmaf(v.y, w1, acc[p]);
                        acc[p] = fmaf(v.z, w2, acc[p]);
                        acc[p] = fmaf(v.w, w3, acc[p]);
                    }
                }
            }
        }
    }

    float* zrow = z + ((size_t)(b * Hh + y) * Ww) * C4;
#pragma unroll
    for (int p = 0; p < 8; ++p) {
        zrow[(size_t)(x0 + p) * C4 + ch] = acc[p];
    }
}

// ---------------------------------------------------------------------------
// Kernel 2: pointwise LSTM update + BN write of layer output into X[:,t]
// c,h updated in place (each element touched by exactly one thread).
// ---------------------------------------------------------------------------
__global__ __launch_bounds__(256) void lstm_point(
    const float* __restrict__ z,      // [B,H,W,160]
    float* __restrict__ c,            // [B,H,W,F]
    float* __restrict__ h,            // [B,H,W,F]
    float* __restrict__ X,            // [B,T,H,W,F]
    const float* __restrict__ gamma_, const float* __restrict__ beta_,
    const float* __restrict__ mu_, const float* __restrict__ var_,
    int t)
{
    const int gid = blockIdx.x * blockDim.x + threadIdx.x;
    if (gid >= Bc * Hh * Ww * Fc) return;
    const int f = gid % Fc;
    const int p = gid / Fc;  // (b*H + y)*W + x

    const float zi = z[(size_t)p * C4 + f];
    const float zf = z[(size_t)p * C4 + 40 + f];
    const float zg = z[(size_t)p * C4 + 80 + f];
    const float zo = z[(size_t)p * C4 + 120 + f];

    const float c_old = c[gid];
    const float c_new = hsig(zf) * c_old + hsig(zi) * tanhf(zg);
    const float h_new = hsig(zo) * tanhf(c_new);
    c[gid] = c_new;
    h[gid] = h_new;

    const int b  = p / (Hh * Ww);
    const int yx = p % (Hh * Ww);
    const float sc = gamma_[f] * rsqrtf(var_[f] + BN_EPS_);
    X[((size_t)(b * Tt + t) * Hh * Ww + yx) * Fc + f] = (h_new - mu_[f]) * sc + beta_[f];
}

// ---------------------------------------------------------------------------
// Kernel 3: Conv3D (3x3x3, SAME over T,H,W) + bias + sigmoid
// ---------------------------------------------------------------------------
__global__ __launch_bounds__(256) void conv3d_sig(
    const float* __restrict__ X,      // [B,T,H,W,F]
    const float* __restrict__ W3,     // [3,3,3,F,1]
    const float* __restrict__ b3,     // [1]
    float* __restrict__ out)          // [B,T,H,W]
{
    __shared__ float ws[27 * Fc];
    for (int i = threadIdx.x; i < 27 * Fc; i += blockDim.x) ws[i] = W3[i];
    __syncthreads();

    const int gid = blockIdx.x * blockDim.x + threadIdx.x;
    if (gid >= Bc * Tt * Hh * Ww) return;
    const int x = gid % Ww;
    const int y = (gid / Ww) % Hh;
    const int t = (gid / (Ww * Hh)) % Tt;
    const int b = gid / (Ww * Hh * Tt);

    float acc = b3[0];
    for (int dt = 0; dt < 3; ++dt) {
        const int tt = t + dt - 1;
        if (tt < 0 || tt >= Tt) continue;
        for (int dy = 0; dy < 3; ++dy) {
            const int yy = y + dy - 1;
            if (yy < 0 || yy >= Hh) continue;
            for (int dx = 0; dx < 3; ++dx) {
                const int xx = x + dx - 1;
                if (xx < 0 || xx >= Ww) continue;
                const float* xp = X + (((size_t)(b * Tt + tt) * Hh + yy) * Ww + xx) * Fc;
                const float* wp = ws + ((dt * 3 + dy) * 3 + dx) * Fc;
#pragma unroll 8
                for (int ci = 0; ci < Fc; ++ci) acc = fmaf(xp[ci], wp[ci], acc);
            }
        }
    }
    out[gid] = 1.0f / (1.0f + expf(-acc));
}

// ---------------------------------------------------------------------------
extern "C" void kernel_launch(void* const* d_in, const int* in_sizes, int n_in,
                              void* d_out, int out_size, void* d_ws, size_t ws_size,
                              hipStream_t stream)
{
    const float* inp = (const float*)d_in[0];

    float* X = (float*)d_ws;               // [B,T,H,W,F]  32,768,000 floats
    float* z = X + (size_t)Bc * Tt * Hh * Ww * Fc;   // [B,H,W,160]   4,096,000
    float* h = z + (size_t)Bc * Hh * Ww * C4;        // [B,H,W,F]     1,024,000
    float* c = h + (size_t)Bc * Hh * Ww * Fc;        // [B,H,W,F]     1,024,000
    // total = 38,912,000 floats = ~148.4 MiB of d_ws

    const dim3 g1(Ww / 8, Hh / 2, Bc);  // (5,20,16)
    const dim3 b1(160, 2);

    for (int l = 0; l < 4; ++l) {
        const float* Wx = (const float*)d_in[1 + 7 * l + 0];
        const float* Wh = (const float*)d_in[1 + 7 * l + 1];
        const float* bi = (const float*)d_in[1 + 7 * l + 2];
        const float* ga = (const float*)d_in[1 + 7 * l + 3];
        const float* be = (const float*)d_in[1 + 7 * l + 4];
        const float* mu = (const float*)d_in[1 + 7 * l + 5];
        const float* va = (const float*)d_in[1 + 7 * l + 6];

        hipMemsetAsync(h, 0, (size_t)Bc * Hh * Ww * Fc * sizeof(float), stream);
        hipMemsetAsync(c, 0, (size_t)Bc * Hh * Ww * Fc * sizeof(float), stream);

        for (int t = 0; t < Tt; ++t) {
            if (l == 0)
                conv_gates<1><<<g1, b1, 0, stream>>>(inp, h, Wx, Wh, bi, z, t);
            else
                conv_gates<40><<<g1, b1, 0, stream>>>(X, h, Wx, Wh, bi, z, t);
            lstm_point<<<(Bc * Hh * Ww * Fc) / 256, 256, 0, stream>>>(
                z, c, h, X, ga, be, mu, va, t);
        }
    }

    conv3d_sig<<<(Bc * Tt * Hh * Ww) / 256, 256, 0, stream>>>(
        X, (const float*)d_in[29], (const float*)d_in[30], (float*)d_out);
}

// Round 2
// 5104.145 us; speedup vs baseline: 15.7032x; 15.7032x over previous
//
#include <hip/hip_runtime.h>
#include <hip/hip_bf16.h>
#include <cstddef>

typedef __attribute__((ext_vector_type(8))) short short8;
typedef __attribute__((ext_vector_type(4))) float f32x4;
typedef unsigned short u16;
typedef unsigned int u32;

#define Bc 16
#define Tt 32
#define Hh 40
#define Ww 40
#define Fc 40
#define NPIX (Bc*Hh*Ww)   // 25600
#define BN_EPS_ 1e-3f

__device__ __forceinline__ float hsig(float x) {
    return fminf(fmaxf(0.2f * x + 0.5f, 0.0f), 1.0f);
}
__device__ __forceinline__ u16 f2b(float f) {
    __hip_bfloat16 h = __float2bfloat16(f);
    return __builtin_bit_cast(u16, h);
}
__device__ __forceinline__ float b2f(u16 u) {
    return __builtin_bit_cast(float, (u32)u << 16);
}

// ---------------------------------------------------------------------------
// Pack [Wx ; Wh] into transposed bf16 weight matrix Wt[160][KPAD],
// K-order = (pos=dy*3+dx major, cc=[x-ch | h-ch] minor), zero-padded to KPAD.
// ---------------------------------------------------------------------------
template <int CIN>
__global__ __launch_bounds__(256) void build_wt(const float* __restrict__ Wx,
                                                const float* __restrict__ Wh,
                                                u16* __restrict__ Wt)
{
    constexpr int KPOS = CIN + Fc;
    constexpr int K    = 9 * KPOS;
    constexpr int KPAD = ((K + 31) / 32) * 32;
    int idx = blockIdx.x * 256 + threadIdx.x;
    if (idx >= 160 * KPAD) return;
    int n = idx / KPAD, k = idx - n * KPAD;
    float v = 0.0f;
    if (k < K) {
        int pos = k / KPOS, cc = k - pos * KPOS;
        v = (cc < CIN) ? Wx[(pos * CIN + cc) * 160 + n]
                       : Wh[(pos * Fc + (cc - CIN)) * 160 + n];
    }
    Wt[idx] = f2b(v);
}

// ---------------------------------------------------------------------------
// One ConvLSTM timestep, fused: implicit-im2col bf16 MFMA GEMM (M=64 tile,
// N=160 full, K=9*(CIN+40)) + LSTM pointwise + BN, writes h (bf16) and
// BN'd layer output X_out (bf16). fp32 accumulators, fp32 cell state.
// Block: 256 thr = 4 waves, wave = 2 M-subtiles x 5 N-subtiles of 16x16x32.
// ---------------------------------------------------------------------------
template <int CIN, bool XF32>
__global__ __launch_bounds__(256) void step_kernel(
    const void* __restrict__ xin_v,   // layer input: fp32 [B,T,H,W,CIN] or bf16 [B,T,H,W,40]
    const u16* __restrict__ h_in,     // bf16 [NPIX,40]
    u16* __restrict__ h_out,          // bf16 [NPIX,40]
    float* __restrict__ c,            // fp32 [NPIX,40]
    const u16* __restrict__ Wt,       // bf16 [160][KPAD]
    const float* __restrict__ bias,   // [160]
    const float* __restrict__ gamma_, const float* __restrict__ beta_,
    const float* __restrict__ mu_,    const float* __restrict__ var_,
    u16* __restrict__ X_out,          // bf16 [B,T,H,W,40]
    int t)
{
    constexpr int KPOS = CIN + Fc;
    constexpr int K    = 9 * KPOS;
    constexpr int NK   = (K + 31) / 32;
    constexpr int KPAD = NK * 32;

    __shared__ __align__(16) u16 As[64][40];    // [m][k-chunk], +8 pad (bank-safe)
    __shared__ __align__(16) u16 Bs[160][40];   // [n][k-chunk], +8 pad
    __shared__ float zs[64][164];               // z tile for epilogue, stride 164 (bank-safe)

    const int tid  = threadIdx.x;
    const int P0   = blockIdx.x * 64;     // 1600 % 64 == 0 -> block never straddles batch
    const int bimg = P0 / 1600;

    // ---- gather-role constants (thread -> (m, k-quad) of A tile) ----
    const int mloc = tid >> 2;            // 0..63
    const int kq   = (tid & 3) * 8;       // 0,8,16,24
    const int p    = P0 + mloc;
    const int yx   = p - bimg * 1600;
    const int gy   = yx / 40;
    const int gx   = yx - gy * 40;

    const float* xf = (const float*)xin_v + (XF32 ? (size_t)(bimg * Tt + t) * 1600 * CIN : 0);
    const u16*   xb = (const u16*)xin_v + (!XF32 ? (size_t)(bimg * Tt + t) * 1600 * Fc : 0);
    const u16*   hp = h_in + (size_t)bimg * 1600 * Fc;

    // ---- MFMA-role constants ----
    const int lane  = tid & 63;
    const int wid   = tid >> 6;           // 0..3
    const int mg    = wid & 1;            // M group (32 rows)
    const int ng    = wid >> 1;           // N group (80 cols)
    const int lcol  = lane & 15;
    const int lquad = lane >> 4;

    f32x4 acc[2][5] = {};

    for (int it = 0; it < NK; ++it) {
        const int k0 = it * 32;
        __syncthreads();  // previous iter's LDS reads complete before overwrite

        // ---- stage A (im2col gather): 8 consecutive k for fixed m ----
        {
            int kk  = k0 + kq;
            int pos = kk / KPOS;
            int cc  = kk - pos * KPOS;
            u16 vals[8];
            int rowoff = 0;
            bool ok = false, need = true;
#pragma unroll
            for (int i = 0; i < 8; ++i) {
                if (need) {
                    int dy = pos / 3, dx = pos - dy * 3;
                    int yy = gy + dy - 1, xx = gx + dx - 1;
                    ok = (pos < 9) && (yy >= 0) && (yy < Hh) && (xx >= 0) && (xx < Ww);
                    rowoff = yy * Ww + xx;
                    need = false;
                }
                u16 v = 0;
                if (ok) {
                    if (cc < CIN) {
                        if (XF32) v = f2b(xf[rowoff * CIN + cc]);
                        else      v = xb[rowoff * Fc + cc];
                    } else {
                        v = hp[rowoff * Fc + (cc - CIN)];
                    }
                }
                vals[i] = v;
                if (++cc == KPOS) { cc = 0; ++pos; need = true; }
            }
            *reinterpret_cast<uint4*>(&As[mloc][kq]) =
                *reinterpret_cast<const uint4*>(vals);
        }

        // ---- stage B: Wt[n][k0..k0+32), contiguous 16B chunks ----
        for (int idx = tid; idx < 640; idx += 256) {
            int n = idx >> 2, q = idx & 3;
            *reinterpret_cast<uint4*>(&Bs[n][q * 8]) =
                *reinterpret_cast<const uint4*>(Wt + (size_t)n * KPAD + k0 + q * 8);
        }
        __syncthreads();

        // ---- fragments + MFMA ----
        short8 afr[2], bfr[5];
#pragma unroll
        for (int mt = 0; mt < 2; ++mt)
            afr[mt] = *reinterpret_cast<const short8*>(&As[mg * 32 + mt * 16 + lcol][lquad * 8]);
#pragma unroll
        for (int nt = 0; nt < 5; ++nt)
            bfr[nt] = *reinterpret_cast<const short8*>(&Bs[ng * 80 + nt * 16 + lcol][lquad * 8]);
#pragma unroll
        for (int mt = 0; mt < 2; ++mt)
#pragma unroll
            for (int nt = 0; nt < 5; ++nt)
                acc[mt][nt] = __builtin_amdgcn_mfma_f32_16x16x32_bf16(
                    afr[mt], bfr[nt], acc[mt][nt], 0, 0, 0);
    }

    // ---- dump z tiles to LDS (C layout: col=lane&15, row=quad*4+reg) ----
#pragma unroll
    for (int mt = 0; mt < 2; ++mt)
#pragma unroll
        for (int nt = 0; nt < 5; ++nt) {
            int mrow = mg * 32 + mt * 16 + lquad * 4;
            int ncol = ng * 80 + nt * 16 + lcol;
#pragma unroll
            for (int r = 0; r < 4; ++r)
                zs[mrow + r][ncol] = acc[mt][nt][r];
        }
    __syncthreads();

    // ---- fused LSTM pointwise + BN epilogue (coalesced: item = m*40+f) ----
    float* crow = c + (size_t)P0 * Fc;
    u16* hrow = h_out + (size_t)P0 * Fc;
    u16* xrow = X_out + (size_t)(bimg * Tt + t) * 1600 * Fc + (size_t)(P0 - bimg * 1600) * Fc;
#pragma unroll
    for (int i = 0; i < 10; ++i) {
        int item = i * 256 + tid;         // 0..2559
        int m = item / 40;
        int f = item - m * 40;
        float zi = zs[m][f]        + bias[f];
        float zf = zs[m][40 + f]   + bias[40 + f];
        float zg = zs[m][80 + f]   + bias[80 + f];
        float zo = zs[m][120 + f]  + bias[120 + f];
        float cold = crow[item];
        float cn = hsig(zf) * cold + hsig(zi) * tanhf(zg);
        float hn = hsig(zo) * tanhf(cn);
        crow[item] = cn;
        hrow[item] = f2b(hn);
        float sc = gamma_[f] * rsqrtf(var_[f] + BN_EPS_);
        xrow[item] = f2b((hn - mu_[f]) * sc + beta_[f]);
    }
}

// ---------------------------------------------------------------------------
// Conv3D (3x3x3 SAME) + bias + sigmoid, bf16 input, fp32 out
// ---------------------------------------------------------------------------
__global__ __launch_bounds__(256) void conv3d_sig_bf16(
    const u16* __restrict__ X,        // bf16 [B,T,H,W,40]
    const float* __restrict__ W3,     // [3,3,3,40,1]
    const float* __restrict__ b3,
    float* __restrict__ out)          // [B,T,H,W]
{
    __shared__ float ws[27 * Fc];
    for (int i = threadIdx.x; i < 27 * Fc; i += 256) ws[i] = W3[i];
    __syncthreads();

    int gid = blockIdx.x * 256 + threadIdx.x;
    if (gid >= Bc * Tt * Hh * Ww) return;
    int x = gid % Ww;
    int y = (gid / Ww) % Hh;
    int tt0 = (gid / (Ww * Hh)) % Tt;
    int b = gid / (Ww * Hh * Tt);

    float acc = b3[0];
    for (int dt = 0; dt < 3; ++dt) {
        int tc = tt0 + dt - 1;
        if (tc < 0 || tc >= Tt) continue;
        for (int dy = 0; dy < 3; ++dy) {
            int yy = y + dy - 1;
            if (yy < 0 || yy >= Hh) continue;
            for (int dx = 0; dx < 3; ++dx) {
                int xx = x + dx - 1;
                if (xx < 0 || xx >= Ww) continue;
                const u16* xp = X + (((size_t)(b * Tt + tc) * Hh + yy) * Ww + xx) * Fc;
                const float* wp = ws + ((dt * 3 + dy) * 3 + dx) * Fc;
#pragma unroll
                for (int c4 = 0; c4 < Fc; c4 += 4) {
                    ushort4 v = *reinterpret_cast<const ushort4*>(xp + c4);
                    acc = fmaf(b2f(v.x), wp[c4 + 0], acc);
                    acc = fmaf(b2f(v.y), wp[c4 + 1], acc);
                    acc = fmaf(b2f(v.z), wp[c4 + 2], acc);
                    acc = fmaf(b2f(v.w), wp[c4 + 3], acc);
                }
            }
        }
    }
    out[gid] = 1.0f / (1.0f + expf(-acc));
}

// ---------------------------------------------------------------------------
extern "C" void kernel_launch(void* const* d_in, const int* in_sizes, int n_in,
                              void* d_out, int out_size, void* d_ws, size_t ws_size,
                              hipStream_t stream)
{
    const float* inp = (const float*)d_in[0];

    char* wsb = (char*)d_ws;
    const size_t xsz = (size_t)Bc * Tt * 1600 * Fc * sizeof(u16);  // 65,536,000
    const size_t hsz = (size_t)NPIX * Fc * sizeof(u16);            //  2,048,000
    const size_t csz = (size_t)NPIX * Fc * sizeof(float);          //  4,096,000
    u16*   Xa = (u16*)(wsb);
    u16*   Xb = (u16*)(wsb + xsz);
    u16*   h0 = (u16*)(wsb + 2 * xsz);
    u16*   h1 = (u16*)(wsb + 2 * xsz + hsz);
    float* cc = (float*)(wsb + 2 * xsz + 2 * hsz);
    u16*   Wt = (u16*)(wsb + 2 * xsz + 2 * hsz + csz);
    // total ~139.9 MB (fits: round-1 used 148 MB of d_ws successfully)

    for (int l = 0; l < 4; ++l) {
        const float* Wx = (const float*)d_in[1 + 7 * l + 0];
        const float* Wh = (const float*)d_in[1 + 7 * l + 1];
        const float* bi = (const float*)d_in[1 + 7 * l + 2];
        const float* ga = (const float*)d_in[1 + 7 * l + 3];
        const float* be = (const float*)d_in[1 + 7 * l + 4];
        const float* mu = (const float*)d_in[1 + 7 * l + 5];
        const float* va = (const float*)d_in[1 + 7 * l + 6];

        if (l == 0) build_wt<1><<<240, 256, 0, stream>>>(Wx, Wh, Wt);
        else        build_wt<40><<<460, 256, 0, stream>>>(Wx, Wh, Wt);

        hipMemsetAsync(h0, 0, hsz, stream);
        hipMemsetAsync(h1, 0, hsz, stream);
        hipMemsetAsync(cc, 0, csz, stream);

        const u16* Xin = (l == 0) ? nullptr : ((l & 1) ? Xa : Xb);
        u16* Xout = (l & 1) ? Xb : Xa;   // l0->Xa, l1->Xb, l2->Xa, l3->Xb

        for (int t = 0; t < Tt; ++t) {
            const u16* hin = (t & 1) ? h1 : h0;
            u16* hout = (t & 1) ? h0 : h1;
            if (l == 0)
                step_kernel<1, true><<<NPIX / 64, 256, 0, stream>>>(
                    inp, hin, hout, cc, Wt, bi, ga, be, mu, va, Xout, t);
            else
                step_kernel<40, false><<<NPIX / 64, 256, 0, stream>>>(
                    Xin, hin, hout, cc, Wt, bi, ga, be, mu, va, Xout, t);
        }
    }

    conv3d_sig_bf16<<<(Bc * Tt * Hh * Ww) / 256, 256, 0, stream>>>(
        Xb, (const float*)d_in[29], (const float*)d_in[30], (float*)d_out);
}

// Round 3
// 3450.187 us; speedup vs baseline: 23.2310x; 1.4794x over previous
//
#include <hip/hip_runtime.h>
#include <hip/hip_bf16.h>
#include <cstddef>

typedef __attribute__((ext_vector_type(8))) short short8;
typedef __attribute__((ext_vector_type(4))) float f32x4;
typedef unsigned short u16;
typedef unsigned int u32;

#define Bc 16
#define Tt 32
#define Hh 40
#define Ww 40
#define Fc 40
#define NPIX (Bc*Hh*Ww)   // 25600
#define BN_EPS_ 1e-3f

__device__ __forceinline__ float hsig(float x) {
    return fminf(fmaxf(0.2f * x + 0.5f, 0.0f), 1.0f);
}
__device__ __forceinline__ u16 f2b(float f) {
    __hip_bfloat16 h = __float2bfloat16(f);
    return __builtin_bit_cast(u16, h);
}
__device__ __forceinline__ float b2f(u16 u) {
    return __builtin_bit_cast(float, (u32)u << 16);
}

// ---------------------------------------------------------------------------
// Pack [Wx ; Wh] -> bf16 Wt[160][KPAD]. K-order: pos (dy*3+dx) major, then
// cc = [x-ch padded to XPAD | h-ch(40)]. Zero pad k in [K, KPAD).
// ---------------------------------------------------------------------------
template <int XPAD, int CIN>
__global__ __launch_bounds__(256) void build_wt(const float* __restrict__ Wx,
                                                const float* __restrict__ Wh,
                                                u16* __restrict__ Wt)
{
    constexpr int KPOS = XPAD + Fc;
    constexpr int K    = 9 * KPOS;
    constexpr int KPAD = ((K + 31) / 32) * 32;
    int idx = blockIdx.x * 256 + threadIdx.x;
    if (idx >= 160 * KPAD) return;
    int n = idx / KPAD, k = idx - n * KPAD;
    float v = 0.0f;
    if (k < K) {
        int pos = k / KPOS, cc = k - pos * KPOS;
        if (cc < XPAD) {
            v = (cc < CIN) ? Wx[(pos * CIN + cc) * 160 + n] : 0.0f;
        } else {
            v = Wh[(pos * Fc + (cc - XPAD)) * 160 + n];
        }
    }
    Wt[idx] = f2b(v);
}

// ---------------------------------------------------------------------------
// One ConvLSTM timestep. LDS halo staging for X_t and h (coalesced loads),
// A fragments built directly from LDS (ds_read_b128), Bs weight chunk
// double-buffered (1 barrier / k-iter). Fused LSTM pointwise + BN epilogue.
// Block: 256 thr = 4 waves; M-tile 64 pixels, N = 160 gates.
// ---------------------------------------------------------------------------
template <int XPAD, bool XF32>
__global__ __launch_bounds__(256, 2) void step_kernel2(
    const void* __restrict__ xin_v,   // fp32 [B,T,1600,CIN=1] or bf16 [B,T,1600,40]
    const u16* __restrict__ h_in,     // bf16 [NPIX,40]
    u16* __restrict__ h_out,          // bf16 [NPIX,40]
    float* __restrict__ c,            // fp32 [NPIX,40]
    const u16* __restrict__ Wt,       // bf16 [160][KPAD]
    const float* __restrict__ bias,   // [160]
    const float* __restrict__ gamma_, const float* __restrict__ beta_,
    const float* __restrict__ mu_,    const float* __restrict__ var_,
    u16* __restrict__ X_out,          // bf16 [B,T,1600,40]
    int t)
{
    constexpr int KPOS = XPAD + Fc;
    constexpr int K    = 9 * KPOS;
    constexpr int NK   = (K + 31) / 32;
    constexpr int KPAD = NK * 32;
    constexpr int XROW = 42 * XPAD;       // u16 per staged X row
    constexpr int HROW = 42 * Fc;
    constexpr int XS_SZ = 5 * XROW;
    constexpr int HS_SZ = 5 * HROW;
    constexpr int BS_STR = 40;            // u16 stride per n-row (pad 32->40)
    constexpr int BS_SZ  = 160 * BS_STR;  // one buffer
    constexpr int SMEM_U16 = XS_SZ + HS_SZ + 2 * BS_SZ;
    static_assert(SMEM_U16 * 2 >= 64 * 164 * 4, "zs overlay must fit");

    __shared__ __align__(16) u16 smem[SMEM_U16];
    u16* Xs  = smem;
    u16* Hs  = smem + XS_SZ;
    u16* Bs0 = smem + XS_SZ + HS_SZ;
    u16* Bs1 = Bs0 + BS_SZ;
    float* zs = reinterpret_cast<float*>(smem);   // [64][164] overlay (epilogue)

    const int tid  = threadIdx.x;
    const int P0   = blockIdx.x * 64;
    const int bimg = P0 / 1600;
    const int P0l  = P0 - bimg * 1600;       // 0..1536, multiple of 64
    const int P0row = P0l / 40;
    const int row0  = P0row - 1;             // first staged global row

    const float* xf = (const float*)xin_v + (XF32 ? (size_t)(bimg * Tt + t) * 1600 : 0);
    const u16*   xb = (const u16*)xin_v + (!XF32 ? (size_t)(bimg * Tt + t) * 1600 * Fc : 0);
    const u16*   hp = h_in + (size_t)bimg * 1600 * Fc;

    // ---- stage h halo: 5 rows x 42 cols x 40 ch (uint2 = 4 bf16) ----
    for (int i = tid; i < 5 * 40 * 10; i += 256) {
        int r = i / 400, rem = i - r * 400;
        int px = rem / 10, c4 = rem - px * 10;
        int gy = row0 + r;
        uint2 v = make_uint2(0u, 0u);
        if (gy >= 0 && gy < Hh)
            v = *reinterpret_cast<const uint2*>(hp + ((size_t)gy * 40 + px) * Fc + c4 * 4);
        *reinterpret_cast<uint2*>(&Hs[r * HROW + (px + 1) * Fc + c4 * 4]) = v;
    }
    for (int i = tid; i < 5 * 2 * 10; i += 256) {   // h x-halo columns
        int r = i / 20, rem = i - r * 20;
        int side = rem / 10, c4 = rem - side * 10;
        *reinterpret_cast<uint2*>(&Hs[r * HROW + (side ? 41 : 0) * Fc + c4 * 4]) =
            make_uint2(0u, 0u);
    }

    // ---- stage X halo ----
    if constexpr (XF32) {
        // layer 0: CIN=1 padded to 8 ch; each thread writes a full 16B group
        for (int i = tid; i < 5 * 42; i += 256) {
            int r = i / 42, xc = i - r * 42;
            int gy = row0 + r, gx = xc - 1;
            u16 tmp[8] = {0, 0, 0, 0, 0, 0, 0, 0};
            if (gy >= 0 && gy < Hh && gx >= 0 && gx < Ww)
                tmp[0] = f2b(xf[(size_t)gy * 40 + gx]);
            *reinterpret_cast<uint4*>(&Xs[(r * 42 + xc) * 8]) =
                *reinterpret_cast<const uint4*>(tmp);
        }
    } else {
        for (int i = tid; i < 5 * 40 * 10; i += 256) {
            int r = i / 400, rem = i - r * 400;
            int px = rem / 10, c4 = rem - px * 10;
            int gy = row0 + r;
            uint2 v = make_uint2(0u, 0u);
            if (gy >= 0 && gy < Hh)
                v = *reinterpret_cast<const uint2*>(xb + ((size_t)gy * 40 + px) * Fc + c4 * 4);
            *reinterpret_cast<uint2*>(&Xs[r * XROW + (px + 1) * Fc + c4 * 4]) = v;
        }
        for (int i = tid; i < 5 * 2 * 10; i += 256) {
            int r = i / 20, rem = i - r * 20;
            int side = rem / 10, c4 = rem - side * 10;
            *reinterpret_cast<uint2*>(&Xs[r * XROW + (side ? 41 : 0) * Fc + c4 * 4]) =
                make_uint2(0u, 0u);
        }
    }

    // ---- preload Bs chunk 0 ----
    for (int idx = tid; idx < 640; idx += 256) {
        int n = idx >> 2, q = idx & 3;
        *reinterpret_cast<uint4*>(&Bs0[n * BS_STR + q * 8]) =
            *reinterpret_cast<const uint4*>(Wt + (size_t)n * KPAD + q * 8);
    }

    // ---- MFMA-role constants ----
    const int lane  = tid & 63;
    const int wid   = tid >> 6;
    const int mg    = wid & 1;
    const int ng    = wid >> 1;
    const int lcol  = lane & 15;
    const int lquad = lane >> 4;

    int rb[2], pxm[2];
#pragma unroll
    for (int mt = 0; mt < 2; ++mt) {
        int m   = mg * 32 + mt * 16 + lcol;
        int lin = P0l + m;
        int py  = lin / 40;
        pxm[mt] = lin - py * 40;
        rb[mt]  = py - P0row;       // 0..2
    }

    f32x4 acc[2][5] = {};

    __syncthreads();

#pragma unroll 2
    for (int it = 0; it < NK; ++it) {
        const u16* BsR = (it & 1) ? Bs1 : Bs0;
        u16*       BsW = (it & 1) ? Bs0 : Bs1;

        // ---- A fragments from staged halo ----
        const int k   = it * 32 + lquad * 8;
        const int pos = k / KPOS;
        const int cc  = k - pos * KPOS;
        short8 afr[2] = {};
        if (pos < 9) {
            const int dy = pos / 3, dx = pos - dy * 3;
            const u16* base;
            int ch, str;
            if (cc < XPAD) { base = Xs; ch = cc;        str = XPAD; }
            else           { base = Hs; ch = cc - XPAD; str = Fc;   }
#pragma unroll
            for (int mt = 0; mt < 2; ++mt) {
                int r  = rb[mt] + dy;            // 0..4
                int xc = pxm[mt] + dx;           // 0..41
                afr[mt] = *reinterpret_cast<const short8*>(&base[(r * 42 + xc) * str + ch]);
            }
        }

        // ---- B fragments ----
        short8 bfr[5];
#pragma unroll
        for (int nt = 0; nt < 5; ++nt)
            bfr[nt] = *reinterpret_cast<const short8*>(
                &BsR[(ng * 80 + nt * 16 + lcol) * BS_STR + lquad * 8]);

        // ---- stage next Bs chunk (other buffer) ----
        if (it + 1 < NK) {
            for (int idx = tid; idx < 640; idx += 256) {
                int n = idx >> 2, q = idx & 3;
                *reinterpret_cast<uint4*>(&BsW[n * BS_STR + q * 8]) =
                    *reinterpret_cast<const uint4*>(Wt + (size_t)n * KPAD + (it + 1) * 32 + q * 8);
            }
        }

#pragma unroll
        for (int mt = 0; mt < 2; ++mt)
#pragma unroll
            for (int nt = 0; nt < 5; ++nt)
                acc[mt][nt] = __builtin_amdgcn_mfma_f32_16x16x32_bf16(
                    afr[mt], bfr[nt], acc[mt][nt], 0, 0, 0);

        __syncthreads();
    }

    // ---- dump z tiles to LDS (C layout: col=lane&15, row=quad*4+reg) ----
#pragma unroll
    for (int mt = 0; mt < 2; ++mt)
#pragma unroll
        for (int nt = 0; nt < 5; ++nt) {
            int mrow = mg * 32 + mt * 16 + lquad * 4;
            int ncol = ng * 80 + nt * 16 + lcol;
#pragma unroll
            for (int r = 0; r < 4; ++r)
                zs[(mrow + r) * 164 + ncol] = acc[mt][nt][r];
        }
    __syncthreads();

    // ---- fused LSTM pointwise + BN epilogue ----
    float* crow = c + (size_t)P0 * Fc;
    u16* hrow = h_out + (size_t)P0 * Fc;
    u16* xrow = X_out + ((size_t)(bimg * Tt + t) * 1600 + P0l) * Fc;
#pragma unroll
    for (int i = 0; i < 10; ++i) {
        int item = i * 256 + tid;         // 0..2559
        int m = item / 40;
        int f = item - m * 40;
        float zi = zs[m * 164 + f]       + bias[f];
        float zf = zs[m * 164 + 40 + f]  + bias[40 + f];
        float zg = zs[m * 164 + 80 + f]  + bias[80 + f];
        float zo = zs[m * 164 + 120 + f] + bias[120 + f];
        float cold = crow[item];
        float cn = hsig(zf) * cold + hsig(zi) * tanhf(zg);
        float hn = hsig(zo) * tanhf(cn);
        crow[item] = cn;
        hrow[item] = f2b(hn);
        float sc = gamma_[f] * rsqrtf(var_[f] + BN_EPS_);
        xrow[item] = f2b((hn - mu_[f]) * sc + beta_[f]);
    }
}

// ---------------------------------------------------------------------------
// Conv3D (3x3x3 SAME) + bias + sigmoid, bf16 in, fp32 out.
// XCD-aware swizzle: xcd = blockIdx % 8 owns 2 batches; consecutive t share L2.
// ---------------------------------------------------------------------------
__global__ __launch_bounds__(320) void conv3d_sig_bf16(
    const u16* __restrict__ X,        // bf16 [B,T,1600,40]
    const float* __restrict__ W3,     // [3,3,3,40,1]
    const float* __restrict__ b3,
    float* __restrict__ out)          // [B,T,1600]
{
    __shared__ float ws[27 * Fc];
    for (int i = threadIdx.x; i < 27 * Fc; i += 320) ws[i] = W3[i];
    __syncthreads();

    const int bid   = blockIdx.x;           // 2560 blocks
    const int xcd   = bid & 7;
    const int local = bid >> 3;             // 0..319
    const int b     = xcd * 2 + (local / 160);
    const int rem   = local - (local / 160) * 160;
    const int t     = rem / 5;
    const int s     = rem - t * 5;
    const int pix   = s * 320 + threadIdx.x;   // 0..1599
    const int y     = pix / 40;
    const int x     = pix - y * 40;

    float acc = b3[0];
    for (int dt = 0; dt < 3; ++dt) {
        int tc = t + dt - 1;
        if (tc < 0 || tc >= Tt) continue;
        for (int dy = 0; dy < 3; ++dy) {
            int yy = y + dy - 1;
            if (yy < 0 || yy >= Hh) continue;
            for (int dx = 0; dx < 3; ++dx) {
                int xx = x + dx - 1;
                if (xx < 0 || xx >= Ww) continue;
                const u16* xp = X + ((size_t)(b * Tt + tc) * 1600 + yy * 40 + xx) * Fc;
                const float* wp = ws + ((dt * 3 + dy) * 3 + dx) * Fc;
#pragma unroll
                for (int c4 = 0; c4 < Fc; c4 += 4) {
                    ushort4 v = *reinterpret_cast<const ushort4*>(xp + c4);
                    acc = fmaf(b2f(v.x), wp[c4 + 0], acc);
                    acc = fmaf(b2f(v.y), wp[c4 + 1], acc);
                    acc = fmaf(b2f(v.z), wp[c4 + 2], acc);
                    acc = fmaf(b2f(v.w), wp[c4 + 3], acc);
                }
            }
        }
    }
    out[((size_t)(b * Tt + t) * 1600 + pix)] = 1.0f / (1.0f + expf(-acc));
}

// ---------------------------------------------------------------------------
extern "C" void kernel_launch(void* const* d_in, const int* in_sizes, int n_in,
                              void* d_out, int out_size, void* d_ws, size_t ws_size,
                              hipStream_t stream)
{
    const float* inp = (const float*)d_in[0];

    char* wsb = (char*)d_ws;
    const size_t xsz = (size_t)Bc * Tt * 1600 * Fc * sizeof(u16);  // 65,536,000
    const size_t hsz = (size_t)NPIX * Fc * sizeof(u16);            //  2,048,000
    const size_t csz = (size_t)NPIX * Fc * sizeof(float);          //  4,096,000
    u16*   Xa = (u16*)(wsb);
    u16*   Xb = (u16*)(wsb + xsz);
    u16*   h0 = (u16*)(wsb + 2 * xsz);
    u16*   h1 = (u16*)(wsb + 2 * xsz + hsz);
    float* cc = (float*)(wsb + 2 * xsz + 2 * hsz);
    u16*   Wt = (u16*)(wsb + 2 * xsz + 2 * hsz + csz);
    // total ~139.8 MB

    for (int l = 0; l < 4; ++l) {
        const float* Wx = (const float*)d_in[1 + 7 * l + 0];
        const float* Wh = (const float*)d_in[1 + 7 * l + 1];
        const float* bi = (const float*)d_in[1 + 7 * l + 2];
        const float* ga = (const float*)d_in[1 + 7 * l + 3];
        const float* be = (const float*)d_in[1 + 7 * l + 4];
        const float* mu = (const float*)d_in[1 + 7 * l + 5];
        const float* va = (const float*)d_in[1 + 7 * l + 6];

        if (l == 0) build_wt<8, 1><<<(160 * 448 + 255) / 256, 256, 0, stream>>>(Wx, Wh, Wt);
        else        build_wt<40, 40><<<(160 * 736 + 255) / 256, 256, 0, stream>>>(Wx, Wh, Wt);

        hipMemsetAsync(h0, 0, hsz, stream);
        hipMemsetAsync(h1, 0, hsz, stream);
        hipMemsetAsync(cc, 0, csz, stream);

        const u16* Xin = (l == 0) ? nullptr : ((l & 1) ? Xa : Xb);
        u16* Xout = (l & 1) ? Xb : Xa;   // l0->Xa, l1->Xb, l2->Xa, l3->Xb

        for (int t = 0; t < Tt; ++t) {
            const u16* hin = (t & 1) ? h1 : h0;
            u16* hout = (t & 1) ? h0 : h1;
            if (l == 0)
                step_kernel2<8, true><<<NPIX / 64, 256, 0, stream>>>(
                    inp, hin, hout, cc, Wt, bi, ga, be, mu, va, Xout, t);
            else
                step_kernel2<40, false><<<NPIX / 64, 256, 0, stream>>>(
                    Xin, hin, hout, cc, Wt, bi, ga, be, mu, va, Xout, t);
        }
    }

    conv3d_sig_bf16<<<2560, 320, 0, stream>>>(
        Xb, (const float*)d_in[29], (const float*)d_in[30], (float*)d_out);
}

// Round 4
// 3222.321 us; speedup vs baseline: 24.8738x; 1.0707x over previous
//
#include <hip/hip_runtime.h>
#include <hip/hip_bf16.h>
#include <cstddef>

typedef __attribute__((ext_vector_type(8))) short short8;
typedef __attribute__((ext_vector_type(4))) float f32x4;
typedef unsigned short u16;
typedef unsigned int u32;

#define Bc 16
#define Tt 32
#define Hh 40
#define Ww 40
#define Fc 40
#define NPIX (Bc*Hh*Ww)   // 25600
#define BN_EPS_ 1e-3f

__device__ __forceinline__ float hsig(float x) {
    return fminf(fmaxf(0.2f * x + 0.5f, 0.0f), 1.0f);
}
__device__ __forceinline__ u16 f2b(float f) {
    __hip_bfloat16 h = __float2bfloat16(f);
    return __builtin_bit_cast(u16, h);
}
__device__ __forceinline__ float b2f(u16 u) {
    return __builtin_bit_cast(float, (u32)u << 16);
}

// ---------------------------------------------------------------------------
// Pack [Wx ; Wh] -> bf16 Wt[160][KPAD]. K-order: pos (dy*3+dx) major, then
// cc = [x-ch padded to XPAD | h-ch(40)]. KPAD rounded to 64. Zero padding.
// ---------------------------------------------------------------------------
template <int XPAD, int CIN>
__global__ __launch_bounds__(256) void build_wt(const float* __restrict__ Wx,
                                                const float* __restrict__ Wh,
                                                u16* __restrict__ Wt)
{
    constexpr int KPOS = XPAD + Fc;
    constexpr int K    = 9 * KPOS;
    constexpr int KPAD = ((K + 63) / 64) * 64;
    int idx = blockIdx.x * 256 + threadIdx.x;
    if (idx >= 160 * KPAD) return;
    int n = idx / KPAD, k = idx - n * KPAD;
    float v = 0.0f;
    if (k < K) {
        int pos = k / KPOS, cc = k - pos * KPOS;
        if (cc < XPAD) {
            v = (cc < CIN) ? Wx[(pos * CIN + cc) * 160 + n] : 0.0f;
        } else {
            v = Wh[(pos * Fc + (cc - XPAD)) * 160 + n];
        }
    }
    Wt[idx] = f2b(v);
}

// ---------------------------------------------------------------------------
// Diagonal-pipelined ConvLSTM step. One launch runs up to 4 (layer, t)
// stages concurrently (all inter-stage deps cross kernel boundaries).
// Per stage: 160 blocks, M-tile = 160 pixels (4 full rows), N = 160 gates,
// implicit-im2col bf16 MFMA GEMM + fused LSTM pointwise + BN epilogue.
// ---------------------------------------------------------------------------
struct Stage {
    const void* xin;   // l==0: fp32 input base; l>=1: bf16 X-ring slot [16][1600][40]
    const u16* hin;    // bf16 [NPIX][40]
    u16*       hout;   // bf16 [NPIX][40]
    float*     cst;    // fp32 [NPIX][40]
    const u16* wt;     // bf16 [160][KPAD]
    const float* bias; const float* ga; const float* be;
    const float* mu;   const float* va;
    u16*       xout;   // l<=2: ring slot [16][1600][40]; l==3: full X3 (t-strided)
    int layer; int t;
};
struct DiagArgs { Stage s[4]; };

__global__ __launch_bounds__(256, 2) void diag_step(DiagArgs args)
{
    constexpr int BS_STR = 72;   // u16 stride (64 + 8 pad): 144B rows, 2-way banks
    // Xs(<=6*42*40) + Hs(6*42*40) + Bs(160*72) = 31680 u16 = 63360 B
    __shared__ __align__(16) u16 smem[6 * 42 * 40 + 6 * 42 * 40 + 160 * BS_STR];

    const int sidx = blockIdx.x / 160;
    const int blk  = blockIdx.x - sidx * 160;
    const Stage& st = args.s[sidx];
    const int l    = st.layer;
    const int XPAD = (l == 0) ? 8 : 40;
    const int KPOS = XPAD + Fc;           // 48 or 80
    const int NKO  = (l == 0) ? 7 : 12;   // outer K-iters of 64
    const int KPAD = NKO * 64;

    u16* Xs = smem;
    u16* Hs = smem + 6 * 42 * XPAD;
    u16* Bs = Hs + 6 * 42 * Fc;
    float* zs = reinterpret_cast<float*>(smem);   // [80][164] overlay (epilogue)

    const int tid   = threadIdx.x;
    const int P0    = blk * 160;           // global pixel base (1600 % 160 == 0)
    const int bimg  = P0 / 1600;
    const int P0l   = P0 - bimg * 1600;
    const int P0row = P0l / 40;            // 0,4,...,36

    // ---- stage Hs halo: 6 rows x 42 cols x 40 ch ----
    const u16* hp = st.hin + (size_t)bimg * 1600 * Fc;
    for (int i = tid; i < 6 * 40 * 10; i += 256) {
        int s = i / 400, rem = i - s * 400;
        int px = rem / 10, c4 = rem - px * 10;
        int gy = P0row - 1 + s;
        uint2 v = make_uint2(0u, 0u);
        if (gy >= 0 && gy < Hh)
            v = *reinterpret_cast<const uint2*>(hp + ((size_t)gy * Ww + px) * Fc + c4 * 4);
        *reinterpret_cast<uint2*>(&Hs[(s * 42 + px + 1) * Fc + c4 * 4]) = v;
    }
    for (int i = tid; i < 6 * 2 * 10; i += 256) {
        int s = i / 20, rem = i - s * 20;
        int side = rem / 10, c4 = rem - side * 10;
        *reinterpret_cast<uint2*>(&Hs[(s * 42 + (side ? 41 : 0)) * Fc + c4 * 4]) =
            make_uint2(0u, 0u);
    }

    // ---- stage Xs halo ----
    if (l == 0) {
        const float* xf = (const float*)st.xin + (size_t)(bimg * Tt + st.t) * 1600;
        for (int i = tid; i < 6 * 42; i += 256) {
            int s = i / 42, xc = i - s * 42;
            int gy = P0row - 1 + s, gx = xc - 1;
            u16 tmp[8] = {0, 0, 0, 0, 0, 0, 0, 0};
            if (gy >= 0 && gy < Hh && gx >= 0 && gx < Ww)
                tmp[0] = f2b(xf[(size_t)gy * Ww + gx]);
            *reinterpret_cast<uint4*>(&Xs[(s * 42 + xc) * 8]) =
                *reinterpret_cast<const uint4*>(tmp);
        }
    } else {
        const u16* xb = (const u16*)st.xin + (size_t)bimg * 1600 * Fc;
        for (int i = tid; i < 6 * 40 * 10; i += 256) {
            int s = i / 400, rem = i - s * 400;
            int px = rem / 10, c4 = rem - px * 10;
            int gy = P0row - 1 + s;
            uint2 v = make_uint2(0u, 0u);
            if (gy >= 0 && gy < Hh)
                v = *reinterpret_cast<const uint2*>(xb + ((size_t)gy * Ww + px) * Fc + c4 * 4);
            *reinterpret_cast<uint2*>(&Xs[(s * 42 + px + 1) * Fc + c4 * 4]) = v;
        }
        for (int i = tid; i < 6 * 2 * 10; i += 256) {
            int s = i / 20, rem = i - s * 20;
            int side = rem / 10, c4 = rem - side * 10;
            *reinterpret_cast<uint2*>(&Xs[(s * 42 + (side ? 41 : 0)) * Fc + c4 * 4]) =
                make_uint2(0u, 0u);
        }
    }

    // ---- MFMA role constants: wave = 80 M-rows (mg) x 80 N-cols (ng) ----
    const int lane  = tid & 63;
    const int wid   = tid >> 6;
    const int mg    = wid & 1;
    const int ng    = wid >> 1;
    const int lcol  = lane & 15;
    const int lquad = lane >> 4;

    int py[5], px[5];
#pragma unroll
    for (int mt = 0; mt < 5; ++mt) {
        int mrow = mg * 80 + mt * 16 + lcol;
        py[mt] = mrow / 40;
        px[mt] = mrow - py[mt] * 40;
    }

    f32x4 acc[5][5] = {};

    __syncthreads();   // halos staged

    for (int it = 0; it < NKO; ++it) {
        // ---- stage Bs chunk: 160 n x 64 k ----
        for (int i = tid; i < 1280; i += 256) {
            int n = i >> 3, q = i & 7;
            *reinterpret_cast<uint4*>(&Bs[n * BS_STR + q * 8]) =
                *reinterpret_cast<const uint4*>(st.wt + (size_t)n * KPAD + it * 64 + q * 8);
        }
        __syncthreads();

#pragma unroll
        for (int ki = 0; ki < 2; ++ki) {
            const int k   = it * 64 + ki * 32 + lquad * 8;
            const int pos = k / KPOS;
            const int cc  = k - pos * KPOS;
            short8 afr[5] = {};
            if (pos < 9) {
                const int dy = pos / 3, dx = pos - dy * 3;
                const u16* base; int ch, str;
                if (cc < XPAD) { base = Xs; ch = cc;        str = XPAD; }
                else           { base = Hs; ch = cc - XPAD; str = Fc;   }
#pragma unroll
                for (int mt = 0; mt < 5; ++mt)
                    afr[mt] = *reinterpret_cast<const short8*>(
                        &base[((py[mt] + dy) * 42 + px[mt] + dx) * str + ch]);
            }
            short8 bfr[5];
#pragma unroll
            for (int nt = 0; nt < 5; ++nt)
                bfr[nt] = *reinterpret_cast<const short8*>(
                    &Bs[(ng * 80 + nt * 16 + lcol) * BS_STR + ki * 32 + lquad * 8]);
#pragma unroll
            for (int mt = 0; mt < 5; ++mt)
#pragma unroll
                for (int nt = 0; nt < 5; ++nt)
                    acc[mt][nt] = __builtin_amdgcn_mfma_f32_16x16x32_bf16(
                        afr[mt], bfr[nt], acc[mt][nt], 0, 0, 0);
        }
        __syncthreads();   // MFMA LDS reads drained before next Bs overwrite
    }

    // ---- epilogue in two 80-row chunks (zs overlays smem) ----
    u16* hob = st.hout;
    float* cb = st.cst;
    u16* xob = (l == 3)
        ? st.xout + ((size_t)(bimg * Tt + st.t) * 1600 + P0l) * Fc
        : st.xout + ((size_t)bimg * 1600 + P0l) * Fc;

    for (int q = 0; q < 2; ++q) {
        if (q) __syncthreads();          // chunk-0 zs reads done before overwrite
        if (mg == q) {
#pragma unroll
            for (int mt = 0; mt < 5; ++mt)
#pragma unroll
                for (int nt = 0; nt < 5; ++nt) {
                    int mr   = mt * 16 + lquad * 4;
                    int ncol = ng * 80 + nt * 16 + lcol;
#pragma unroll
                    for (int r = 0; r < 4; ++r)
                        zs[(mr + r) * 164 + ncol] = acc[mt][nt][r];
                }
        }
        __syncthreads();
        for (int i = tid; i < 3200; i += 256) {
            int m = i / 40, f = i - m * 40;
            float zi = zs[m * 164 + f]        + st.bias[f];
            float zf = zs[m * 164 + 40 + f]   + st.bias[40 + f];
            float zg = zs[m * 164 + 80 + f]   + st.bias[80 + f];
            float zo = zs[m * 164 + 120 + f]  + st.bias[120 + f];
            int pl = q * 80 + m;                       // pixel within block tile
            size_t gp = (size_t)(P0 + pl) * Fc + f;    // global [pixel][ch]
            float cold = cb[gp];
            float cn = hsig(zf) * cold + hsig(zi) * tanhf(zg);
            float hn = hsig(zo) * tanhf(cn);
            cb[gp] = cn;
            hob[gp] = f2b(hn);
            float sc = st.ga[f] * rsqrtf(st.va[f] + BN_EPS_);
            xob[(size_t)pl * Fc + f] = f2b((hn - st.mu[f]) * sc + st.be[f]);
        }
    }
}

// ---------------------------------------------------------------------------
// Conv3D (3x3x3 SAME) + bias + sigmoid, bf16 in, fp32 out. XCD-aware swizzle.
// ---------------------------------------------------------------------------
__global__ __launch_bounds__(320) void conv3d_sig_bf16(
    const u16* __restrict__ X,        // bf16 [B,T,1600,40]
    const float* __restrict__ W3,     // [3,3,3,40,1]
    const float* __restrict__ b3,
    float* __restrict__ out)          // [B,T,1600]
{
    __shared__ float ws[27 * Fc];
    for (int i = threadIdx.x; i < 27 * Fc; i += 320) ws[i] = W3[i];
    __syncthreads();

    const int bid   = blockIdx.x;           // 2560 blocks
    const int xcd   = bid & 7;
    const int local = bid >> 3;             // 0..319
    const int b     = xcd * 2 + (local / 160);
    const int rem   = local - (local / 160) * 160;
    const int t     = rem / 5;
    const int s     = rem - t * 5;
    const int pix   = s * 320 + threadIdx.x;
    const int y     = pix / 40;
    const int x     = pix - y * 40;

    float acc = b3[0];
    for (int dt = 0; dt < 3; ++dt) {
        int tc = t + dt - 1;
        if (tc < 0 || tc >= Tt) continue;
        for (int dy = 0; dy < 3; ++dy) {
            int yy = y + dy - 1;
            if (yy < 0 || yy >= Hh) continue;
            for (int dx = 0; dx < 3; ++dx) {
                int xx = x + dx - 1;
                if (xx < 0 || xx >= Ww) continue;
                const u16* xp = X + ((size_t)(b * Tt + tc) * 1600 + yy * 40 + xx) * Fc;
                const float* wp = ws + ((dt * 3 + dy) * 3 + dx) * Fc;
#pragma unroll
                for (int c4 = 0; c4 < Fc; c4 += 4) {
                    ushort4 v = *reinterpret_cast<const ushort4*>(xp + c4);
                    acc = fmaf(b2f(v.x), wp[c4 + 0], acc);
                    acc = fmaf(b2f(v.y), wp[c4 + 1], acc);
                    acc = fmaf(b2f(v.z), wp[c4 + 2], acc);
                    acc = fmaf(b2f(v.w), wp[c4 + 3], acc);
                }
            }
        }
    }
    out[((size_t)(b * Tt + t) * 1600 + pix)] = 1.0f / (1.0f + expf(-acc));
}

// ---------------------------------------------------------------------------
extern "C" void kernel_launch(void* const* d_in, const int* in_sizes, int n_in,
                              void* d_out, int out_size, void* d_ws, size_t ws_size,
                              hipStream_t stream)
{
    const float* inp = (const float*)d_in[0];

    char* p = (char*)d_ws;
    const size_t x3sz   = (size_t)Bc * Tt * 1600 * Fc * sizeof(u16);  // 65,536,000
    const size_t slotsz = (size_t)Bc * 1600 * Fc * sizeof(u16);       //  2,048,000
    const size_t csz    = (size_t)NPIX * Fc * sizeof(float);          //  4,096,000
    const size_t wtsz   = (size_t)768 * 160 * sizeof(u16);            //    245,760

    u16* X3 = (u16*)p;                       p += x3sz;
    u16* xr[3];
    for (int l = 0; l < 3; ++l) { xr[l] = (u16*)p; p += 2 * slotsz; }   // ring depth 2
    u16* hb[8];
    for (int i = 0; i < 8; ++i) { hb[i] = (u16*)p; p += slotsz; }
    float* cbuf[4];
    for (int l = 0; l < 4; ++l) { cbuf[l] = (float*)p; p += csz; }
    u16* wt[4];
    for (int l = 0; l < 4; ++l) { wt[l] = (u16*)p; p += wtsz; }
    // total ~112 MB

    // ---- weight packing + state init (all up-front, off the critical chain) ----
    for (int l = 0; l < 4; ++l) {
        const float* Wx = (const float*)d_in[1 + 7 * l + 0];
        const float* Wh = (const float*)d_in[1 + 7 * l + 1];
        if (l == 0) build_wt<8, 1><<<(160 * 448 + 255) / 256, 256, 0, stream>>>(Wx, Wh, wt[l]);
        else        build_wt<40, 40><<<(160 * 768 + 255) / 256, 256, 0, stream>>>(Wx, Wh, wt[l]);
        hipMemsetAsync(hb[l * 2], 0, slotsz, stream);     // h[l][slot 0] (read at t=0)
        hipMemsetAsync(cbuf[l], 0, csz, stream);
    }

    // ---- 35 diagonals: d = l + t ----
    for (int d = 0; d < Tt + 3; ++d) {
        DiagArgs da;
        int na = 0;
        for (int l = 0; l < 4; ++l) {
            int t = d - l;
            if (t < 0 || t >= Tt) continue;
            Stage& s = da.s[na++];
            s.layer = l; s.t = t;
            s.hin  = hb[l * 2 + (t & 1)];
            s.hout = hb[l * 2 + ((t + 1) & 1)];
            s.cst  = cbuf[l];
            s.wt   = wt[l];
            s.bias = (const float*)d_in[1 + 7 * l + 2];
            s.ga   = (const float*)d_in[1 + 7 * l + 3];
            s.be   = (const float*)d_in[1 + 7 * l + 4];
            s.mu   = (const float*)d_in[1 + 7 * l + 5];
            s.va   = (const float*)d_in[1 + 7 * l + 6];
            s.xin  = (l == 0) ? (const void*)inp
                              : (const void*)(xr[l - 1] + (size_t)(t & 1) * (slotsz / 2));
            s.xout = (l == 3) ? X3 : xr[l] + (size_t)(t & 1) * (slotsz / 2);
        }
        diag_step<<<na * 160, 256, 0, stream>>>(da);
    }

    conv3d_sig_bf16<<<2560, 320, 0, stream>>>(
        X3, (const float*)d_in[29], (const float*)d_in[30], (float*)d_out);
}

// Round 5
// 1848.527 us; speedup vs baseline: 43.3595x; 1.7432x over previous
//
#include <hip/hip_runtime.h>
#include <hip/hip_bf16.h>
#include <cstddef>

typedef __attribute__((ext_vector_type(8))) short short8;
typedef __attribute__((ext_vector_type(4))) float f32x4;
typedef unsigned short u16;
typedef unsigned int u32;

#define Bc 16
#define Tt 32
#define Hh 40
#define Ww 40
#define Fc 40
#define NPIX (Bc*Hh*Ww)   // 25600
#define BN_EPS_ 1e-3f

__device__ __forceinline__ float hsig(float x) {
    return fminf(fmaxf(0.2f * x + 0.5f, 0.0f), 1.0f);
}
__device__ __forceinline__ u16 f2b(float f) {
    __hip_bfloat16 h = __float2bfloat16(f);
    return __builtin_bit_cast(u16, h);
}
__device__ __forceinline__ float b2f(u16 u) {
    return __builtin_bit_cast(float, (u32)u << 16);
}

// ---------------------------------------------------------------------------
// Pack [Wx ; Wh] -> bf16 weights in per-wave MFMA B-fragment order:
//   idx = ((((ng*NKO2 + step)*5 + nt)*64 + lane)*8 + j)
//   n = ng*80 + nt*16 + (lane&15);  k = step*32 + (lane>>4)*8 + j
//   k -> pos = k/KPOS, cc = k%KPOS; cc<XPAD -> Wx[pos][cc][n] else Wh[pos][cc-XPAD][n]
// A wave's B-fragment load becomes ONE coalesced global_load_dwordx4.
// ---------------------------------------------------------------------------
template <int XPAD, int CIN, int NKO2>
__global__ __launch_bounds__(256) void build_wf(const float* __restrict__ Wx,
                                                const float* __restrict__ Wh,
                                                u16* __restrict__ Wf)
{
    constexpr int KPOS = XPAD + Fc;
    constexpr int K    = 9 * KPOS;
    int idx = blockIdx.x * 256 + threadIdx.x;
    if (idx >= 2 * NKO2 * 5 * 64 * 8) return;
    int j    = idx & 7;
    int lane = (idx >> 3) & 63;
    int rest = idx >> 9;
    int nt   = rest % 5;  rest /= 5;
    int step = rest % NKO2; rest /= NKO2;
    int ng   = rest;
    int n = ng * 80 + nt * 16 + (lane & 15);
    int k = step * 32 + (lane >> 4) * 8 + j;
    float v = 0.0f;
    if (k < K) {
        int pos = k / KPOS, cc = k - pos * KPOS;
        if (cc < XPAD) {
            v = (cc < CIN) ? Wx[(pos * CIN + cc) * 160 + n] : 0.0f;
        } else {
            v = Wh[(pos * Fc + (cc - XPAD)) * 160 + n];
        }
    }
    Wf[idx] = f2b(v);
}

// ---------------------------------------------------------------------------
// Barrier-free K-loop: B fragments streamed from L2 (coalesced dwordx4),
// A fragments from LDS halo. 25 MFMA per step, no __syncthreads inside.
// ---------------------------------------------------------------------------
template <int KPOS, int XPAD, int NKO2>
__device__ __forceinline__ void kloop(const u16* __restrict__ Xs,
                                      const u16* __restrict__ Hs,
                                      const u16* __restrict__ wf,
                                      const int* py, const int* px,
                                      int lquad, f32x4 acc[5][5])
{
#pragma unroll 2
    for (int step = 0; step < NKO2; ++step) {
        short8 bfr[5];
#pragma unroll
        for (int nt = 0; nt < 5; ++nt)
            bfr[nt] = *reinterpret_cast<const short8*>(wf + (size_t)(step * 5 + nt) * 512);

        const int k   = step * 32 + lquad * 8;
        const int pos = k / KPOS;             // compile-time KPOS -> magic mul
        const int cc  = k - pos * KPOS;
        short8 afr[5] = {};
        if (pos < 9) {
            const int dy = pos / 3, dx = pos - dy * 3;
            const u16* base; int ch, str;
            if (cc < XPAD) { base = Xs; ch = cc;        str = XPAD; }
            else           { base = Hs; ch = cc - XPAD; str = Fc;   }
#pragma unroll
            for (int mt = 0; mt < 5; ++mt)
                afr[mt] = *reinterpret_cast<const short8*>(
                    &base[((py[mt] + dy) * 42 + px[mt] + dx) * str + ch]);
        }
#pragma unroll
        for (int mt = 0; mt < 5; ++mt)
#pragma unroll
            for (int nt = 0; nt < 5; ++nt)
                acc[mt][nt] = __builtin_amdgcn_mfma_f32_16x16x32_bf16(
                    afr[mt], bfr[nt], acc[mt][nt], 0, 0, 0);
    }
}

// ---------------------------------------------------------------------------
// Diagonal-pipelined ConvLSTM step: up to 4 (layer,t) stages per launch.
// Per stage: 160 blocks, M-tile 160 pixels (4 rows), N=160 gates.
// ---------------------------------------------------------------------------
struct Stage {
    const void* xin;   // l==0: fp32 input base; l>=1: bf16 X-ring slot
    const u16* hin;    // bf16 [NPIX][40]
    u16*       hout;
    float*     cst;    // fp32 [NPIX][40]
    const u16* wf;     // fragment-ordered weights
    const float* bias; const float* ga; const float* be;
    const float* mu;   const float* va;
    u16*       xout;
    int layer; int t;
};
struct DiagArgs { Stage s[4]; };

__global__ __launch_bounds__(256, 3) void diag_step(DiagArgs args)
{
    // max(halo 40320 B, zs 80*164*4 = 52480 B) -> 52.5 KB => 3 blocks/CU
    __shared__ __align__(16) u16 smem[26240];

    const int sidx = blockIdx.x / 160;
    const int blk  = blockIdx.x - sidx * 160;
    const Stage& st = args.s[sidx];
    const int l    = st.layer;
    const int XPAD = (l == 0) ? 8 : 40;

    u16* Xs = smem;
    u16* Hs = smem + 6 * 42 * XPAD;
    float* zs = reinterpret_cast<float*>(smem);   // epilogue overlay

    const int tid   = threadIdx.x;
    const int P0    = blk * 160;
    const int bimg  = P0 / 1600;
    const int P0l   = P0 - bimg * 1600;
    const int P0row = P0l / 40;            // 0,4,...,36

    // ---- stage Hs halo: 6 rows x 42 cols x 40 ch ----
    const u16* hp = st.hin + (size_t)bimg * 1600 * Fc;
    for (int i = tid; i < 6 * 40 * 10; i += 256) {
        int s = i / 400, rem = i - s * 400;
        int px_ = rem / 10, c4 = rem - px_ * 10;
        int gy = P0row - 1 + s;
        uint2 v = make_uint2(0u, 0u);
        if (gy >= 0 && gy < Hh)
            v = *reinterpret_cast<const uint2*>(hp + ((size_t)gy * Ww + px_) * Fc + c4 * 4);
        *reinterpret_cast<uint2*>(&Hs[(s * 42 + px_ + 1) * Fc + c4 * 4]) = v;
    }
    for (int i = tid; i < 6 * 2 * 10; i += 256) {
        int s = i / 20, rem = i - s * 20;
        int side = rem / 10, c4 = rem - side * 10;
        *reinterpret_cast<uint2*>(&Hs[(s * 42 + (side ? 41 : 0)) * Fc + c4 * 4]) =
            make_uint2(0u, 0u);
    }

    // ---- stage Xs halo ----
    if (l == 0) {
        const float* xf = (const float*)st.xin + (size_t)(bimg * Tt + st.t) * 1600;
        for (int i = tid; i < 6 * 42; i += 256) {
            int s = i / 42, xc = i - s * 42;
            int gy = P0row - 1 + s, gx = xc - 1;
            u16 tmp[8] = {0, 0, 0, 0, 0, 0, 0, 0};
            if (gy >= 0 && gy < Hh && gx >= 0 && gx < Ww)
                tmp[0] = f2b(xf[(size_t)gy * Ww + gx]);
            *reinterpret_cast<uint4*>(&Xs[(s * 42 + xc) * 8]) =
                *reinterpret_cast<const uint4*>(tmp);
        }
    } else {
        const u16* xb = (const u16*)st.xin + (size_t)bimg * 1600 * Fc;
        for (int i = tid; i < 6 * 40 * 10; i += 256) {
            int s = i / 400, rem = i - s * 400;
            int px_ = rem / 10, c4 = rem - px_ * 10;
            int gy = P0row - 1 + s;
            uint2 v = make_uint2(0u, 0u);
            if (gy >= 0 && gy < Hh)
                v = *reinterpret_cast<const uint2*>(xb + ((size_t)gy * Ww + px_) * Fc + c4 * 4);
            *reinterpret_cast<uint2*>(&Xs[(s * 42 + px_ + 1) * Fc + c4 * 4]) = v;
        }
        for (int i = tid; i < 6 * 2 * 10; i += 256) {
            int s = i / 20, rem = i - s * 20;
            int side = rem / 10, c4 = rem - side * 10;
            *reinterpret_cast<uint2*>(&Xs[(s * 42 + (side ? 41 : 0)) * Fc + c4 * 4]) =
                make_uint2(0u, 0u);
        }
    }

    // ---- wave constants ----
    const int lane  = tid & 63;
    const int wid   = tid >> 6;
    const int mg    = wid & 1;
    const int ng    = wid >> 1;
    const int lcol  = lane & 15;
    const int lquad = lane >> 4;

    int py[5], px[5];
#pragma unroll
    for (int mt = 0; mt < 5; ++mt) {
        int mrow = mg * 80 + mt * 16 + lcol;
        py[mt] = mrow / 40;
        px[mt] = mrow - py[mt] * 40;
    }

    f32x4 acc[5][5] = {};

    __syncthreads();   // halos staged; K-loop is barrier-free

    if (l == 0) {
        const u16* wf = st.wf + ((size_t)ng * 14 * 5 + 0) * 512 + (size_t)lane * 8;
        kloop<48, 8, 14>(Xs, Hs, wf, py, px, lquad, acc);
    } else {
        const u16* wf = st.wf + ((size_t)ng * 24 * 5 + 0) * 512 + (size_t)lane * 8;
        kloop<80, 40, 24>(Xs, Hs, wf, py, px, lquad, acc);
    }

    __syncthreads();   // all waves done reading halo LDS before zs overlay

    // ---- epilogue in two 80-row chunks (zs overlays smem) ----
    u16* hob = st.hout;
    float* cb = st.cst;
    u16* xob = (l == 3)
        ? st.xout + ((size_t)(bimg * Tt + st.t) * 1600 + P0l) * Fc
        : st.xout + ((size_t)bimg * 1600 + P0l) * Fc;

    for (int q = 0; q < 2; ++q) {
        if (mg == q) {
#pragma unroll
            for (int mt = 0; mt < 5; ++mt)
#pragma unroll
                for (int nt = 0; nt < 5; ++nt) {
                    int mr   = mt * 16 + lquad * 4;
                    int ncol = ng * 80 + nt * 16 + lcol;
#pragma unroll
                    for (int r = 0; r < 4; ++r)
                        zs[(mr + r) * 164 + ncol] = acc[mt][nt][r];
                }
        }
        __syncthreads();
        for (int i = tid; i < 3200; i += 256) {
            int m = i / 40, f = i - m * 40;
            float zi = zs[m * 164 + f]        + st.bias[f];
            float zf = zs[m * 164 + 40 + f]   + st.bias[40 + f];
            float zg = zs[m * 164 + 80 + f]   + st.bias[80 + f];
            float zo = zs[m * 164 + 120 + f]  + st.bias[120 + f];
            int pl = q * 80 + m;
            size_t gp = (size_t)(P0 + pl) * Fc + f;
            float cold = cb[gp];
            float cn = hsig(zf) * cold + hsig(zi) * tanhf(zg);
            float hn = hsig(zo) * tanhf(cn);
            cb[gp] = cn;
            hob[gp] = f2b(hn);
            float sc = st.ga[f] * rsqrtf(st.va[f] + BN_EPS_);
            xob[(size_t)pl * Fc + f] = f2b((hn - st.mu[f]) * sc + st.be[f]);
        }
        __syncthreads();   // zs reads done before next chunk's overwrite
    }
}

// ---------------------------------------------------------------------------
// Conv3D (3x3x3 SAME) + bias + sigmoid, bf16 in, fp32 out. XCD-aware swizzle.
// ---------------------------------------------------------------------------
__global__ __launch_bounds__(320) void conv3d_sig_bf16(
    const u16* __restrict__ X,        // bf16 [B,T,1600,40]
    const float* __restrict__ W3,     // [3,3,3,40,1]
    const float* __restrict__ b3,
    float* __restrict__ out)          // [B,T,1600]
{
    __shared__ float ws[27 * Fc];
    for (int i = threadIdx.x; i < 27 * Fc; i += 320) ws[i] = W3[i];
    __syncthreads();

    const int bid   = blockIdx.x;           // 2560 blocks
    const int xcd   = bid & 7;
    const int local = bid >> 3;             // 0..319
    const int b     = xcd * 2 + (local / 160);
    const int rem   = local - (local / 160) * 160;
    const int t     = rem / 5;
    const int s     = rem - t * 5;
    const int pix   = s * 320 + threadIdx.x;
    const int y     = pix / 40;
    const int x     = pix - y * 40;

    float acc = b3[0];
    for (int dt = 0; dt < 3; ++dt) {
        int tc = t + dt - 1;
        if (tc < 0 || tc >= Tt) continue;
        for (int dy = 0; dy < 3; ++dy) {
            int yy = y + dy - 1;
            if (yy < 0 || yy >= Hh) continue;
            for (int dx = 0; dx < 3; ++dx) {
                int xx = x + dx - 1;
                if (xx < 0 || xx >= Ww) continue;
                const u16* xp = X + ((size_t)(b * Tt + tc) * 1600 + yy * 40 + xx) * Fc;
                const float* wp = ws + ((dt * 3 + dy) * 3 + dx) * Fc;
#pragma unroll
                for (int c4 = 0; c4 < Fc; c4 += 4) {
                    ushort4 v = *reinterpret_cast<const ushort4*>(xp + c4);
                    acc = fmaf(b2f(v.x), wp[c4 + 0], acc);
                    acc = fmaf(b2f(v.y), wp[c4 + 1], acc);
                    acc = fmaf(b2f(v.z), wp[c4 + 2], acc);
                    acc = fmaf(b2f(v.w), wp[c4 + 3], acc);
                }
            }
        }
    }
    out[((size_t)(b * Tt + t) * 1600 + pix)] = 1.0f / (1.0f + expf(-acc));
}

// ---------------------------------------------------------------------------
extern "C" void kernel_launch(void* const* d_in, const int* in_sizes, int n_in,
                              void* d_out, int out_size, void* d_ws, size_t ws_size,
                              hipStream_t stream)
{
    const float* inp = (const float*)d_in[0];

    char* p = (char*)d_ws;
    const size_t x3sz   = (size_t)Bc * Tt * 1600 * Fc * sizeof(u16);  // 65,536,000
    const size_t slotsz = (size_t)Bc * 1600 * Fc * sizeof(u16);       //  2,048,000
    const size_t csz    = (size_t)NPIX * Fc * sizeof(float);          //  4,096,000
    const size_t wfsz   = (size_t)2 * 24 * 5 * 64 * 8 * sizeof(u16);  //    245,760

    u16* X3 = (u16*)p;                       p += x3sz;
    u16* xr[3];
    for (int l = 0; l < 3; ++l) { xr[l] = (u16*)p; p += 2 * slotsz; }
    u16* hb[8];
    for (int i = 0; i < 8; ++i) { hb[i] = (u16*)p; p += slotsz; }
    float* cbuf[4];
    for (int l = 0; l < 4; ++l) { cbuf[l] = (float*)p; p += csz; }
    u16* wf[4];
    for (int l = 0; l < 4; ++l) { wf[l] = (u16*)p; p += wfsz; }
    // total ~112 MB

    for (int l = 0; l < 4; ++l) {
        const float* Wx = (const float*)d_in[1 + 7 * l + 0];
        const float* Wh = (const float*)d_in[1 + 7 * l + 1];
        if (l == 0)
            build_wf<8, 1, 14><<<(2 * 14 * 5 * 512 + 255) / 256, 256, 0, stream>>>(Wx, Wh, wf[l]);
        else
            build_wf<40, 40, 24><<<(2 * 24 * 5 * 512 + 255) / 256, 256, 0, stream>>>(Wx, Wh, wf[l]);
        hipMemsetAsync(hb[l * 2], 0, slotsz, stream);
        hipMemsetAsync(cbuf[l], 0, csz, stream);
    }

    // ---- 35 diagonals: d = l + t ----
    for (int d = 0; d < Tt + 3; ++d) {
        DiagArgs da;
        int na = 0;
        for (int l = 0; l < 4; ++l) {
            int t = d - l;
            if (t < 0 || t >= Tt) continue;
            Stage& s = da.s[na++];
            s.layer = l; s.t = t;
            s.hin  = hb[l * 2 + (t & 1)];
            s.hout = hb[l * 2 + ((t + 1) & 1)];
            s.cst  = cbuf[l];
            s.wf   = wf[l];
            s.bias = (const float*)d_in[1 + 7 * l + 2];
            s.ga   = (const float*)d_in[1 + 7 * l + 3];
            s.be   = (const float*)d_in[1 + 7 * l + 4];
            s.mu   = (const float*)d_in[1 + 7 * l + 5];
            s.va   = (const float*)d_in[1 + 7 * l + 6];
            s.xin  = (l == 0) ? (const void*)inp
                              : (const void*)(xr[l - 1] + (size_t)(t & 1) * (slotsz / 2));
            s.xout = (l == 3) ? X3 : xr[l] + (size_t)(t & 1) * (slotsz / 2);
        }
        diag_step<<<na * 160, 256, 0, stream>>>(da);
    }

    conv3d_sig_bf16<<<2560, 320, 0, stream>>>(
        X3, (const float*)d_in[29], (const float*)d_in[30], (float*)d_out);
}